// Round 1
// baseline (207.851 us; speedup 1.0000x reference)
//
#include <hip/hip_runtime.h>
#include <stdint.h>

#define B_ 32
#define P_ 8732
#define C_ 21
#define TOPK 200
#define CONF_T 0.01f
#define NMS_T 0.45f
#define NCH 69  // ceil(8732/128)

__device__ __forceinline__ uint32_t f2s(float f) {
    uint32_t u = __float_as_uint(f);
    return (u & 0x80000000u) ? ~u : (u | 0x80000000u);
}
__device__ __forceinline__ float s2f(uint32_t s) {
    uint32_t b = (s & 0x80000000u) ? (s & 0x7FFFFFFFu) : ~s;
    return __uint_as_float(b);
}

// conf (B,P,C) -> (B,C,P) for coalesced per-task score reads
__global__ __launch_bounds__(256) void transpose_conf(const float* __restrict__ conf,
                                                      float* __restrict__ out) {
    const int TILE = 128;
    int b = blockIdx.x / NCH;
    int ch = blockIdx.x % NCH;
    int p0 = ch * TILE;
    int n = min(TILE, P_ - p0);
    __shared__ float tile[TILE * C_];
    const float* src = conf + ((size_t)b * P_ + p0) * C_;
    for (int i = threadIdx.x; i < n * C_; i += 256) tile[i] = src[i];
    __syncthreads();
    float* dst = out + (size_t)b * C_ * P_ + p0;
    for (int i = threadIdx.x; i < n * C_; i += 256) {
        int c = i / n;
        int k = i - c * n;
        dst[(size_t)c * P_ + k] = tile[k * C_ + c];
    }
}

__global__ __launch_bounds__(256) void detect_kernel(
    const float* __restrict__ loc, const float* __restrict__ prior,
    const float* __restrict__ scores_base, int sstride,
    float* __restrict__ out)
{
    const int task = blockIdx.x;
    const int b = task / C_;
    const int c = task % C_;
    const int tid = threadIdx.x;
    float* outp = out + (size_t)task * TOPK * 5;

    if (c == 0) {  // out.at[:,0].set(0.0)
        for (int e = tid; e < TOPK * 5; e += 256) outp[e] = 0.0f;
        return;
    }

    __shared__ uint32_t sval[P_];           // 34928 B
    __shared__ uint32_t hist[256];
    __shared__ uint64_t cand[256];
    __shared__ int s_cnt;
    __shared__ uint32_t s_pref, s_want;
    __shared__ float bs[TOPK], bx1[TOPK], by1[TOPK], bx2[TOPK], by2[TOPK], bar[TOPK];
    __shared__ unsigned long long msk[TOPK * 4];  // per-j suppression bitmask
    __shared__ unsigned long long vmask[4];
    __shared__ int order[TOPK];
    __shared__ int s_nk;

    // ---- load scores, apply conf threshold, store sortable keys ----
    const float* sp;
    if (sstride == 1) sp = scores_base + ((size_t)b * C_ + c) * (size_t)P_;
    else              sp = scores_base + ((size_t)b * P_) * C_ + c;
    for (int p = tid; p < P_; p += 256) {
        float v = sp[(size_t)p * sstride];
        v = (v > CONF_T) ? v : -1.0f;
        sval[p] = f2s(v);
    }

    // ---- radix-select the 200th largest value (exact 32-bit key) ----
    uint32_t pref = 0, want = TOPK;
    for (int level = 3; level >= 0; --level) {
        const int shift = level * 8;
        const uint32_t himask = (level == 3) ? 0u : (0xFFFFFFFFu << (shift + 8));
        hist[tid] = 0;
        __syncthreads();   // also covers sval visibility on first pass
        for (int p = tid; p < P_; p += 256) {
            uint32_t u = sval[p];
            if ((u & himask) == pref) atomicAdd(&hist[(u >> shift) & 0xFFu], 1u);
        }
        __syncthreads();
        if (tid == 0) {
            uint32_t cum = 0; int bin = 255;
            for (;; --bin) {
                uint32_t h = hist[bin];
                if (cum + h >= want || bin == 0) break;
                cum += h;
            }
            s_pref = pref | ((uint32_t)bin << shift);
            s_want = want - cum;
        }
        __syncthreads();
        pref = s_pref; want = s_want;
    }
    const uint32_t vthr = pref;  // value of the 200th-largest element

    // ---- compact all candidates >= vthr (count in [200,256] w.o.p.) ----
    if (tid == 0) s_cnt = 0;
    __syncthreads();
    for (int p = tid; p < P_; p += 256) {
        uint32_t u = sval[p];
        if (u >= vthr) {
            int pos = atomicAdd(&s_cnt, 1);
            if (pos < 256) cand[pos] = ((uint64_t)u << 32) | (uint32_t)(~(uint32_t)p);
        }
    }
    __syncthreads();
    if (tid >= s_cnt) cand[tid] = 0ull;  // pad sorts to the end
    __syncthreads();

    // ---- bitonic sort 256 keys descending: (value desc, index asc) == jax.lax.top_k ----
    for (int k = 2; k <= 256; k <<= 1) {
        for (int j = k >> 1; j > 0; j >>= 1) {
            int ixj = tid ^ j;
            if (ixj > tid) {
                uint64_t a = cand[tid], bb = cand[ixj];
                bool desc = ((tid & k) == 0);
                bool swap = desc ? (a < bb) : (a > bb);
                if (swap) { cand[tid] = bb; cand[ixj] = a; }
            }
            __syncthreads();
        }
    }

    // ---- decode the top-200 boxes (exact ref f32 op order; no FMA contraction) ----
    for (int i = tid; i < TOPK * 4; i += 256) msk[i] = 0ull;
    if (tid < 4) vmask[tid] = 0ull;
    float my_sc = -1.0f;
    if (tid < TOPK) {
        uint64_t key = cand[tid];
        uint32_t su = (uint32_t)(key >> 32);
        int p = (int)(~(uint32_t)key);
        my_sc = s2f(su);
        const float4 l4 = *(const float4*)(loc + ((size_t)b * P_ + p) * 4);
        const float4 pr = *(const float4*)(prior + (size_t)p * 4);
        float cx = __fadd_rn(pr.x, __fmul_rn(__fmul_rn(l4.x, 0.1f), pr.z));
        float cy = __fadd_rn(pr.y, __fmul_rn(__fmul_rn(l4.y, 0.1f), pr.w));
        float ew = (float)exp((double)__fmul_rn(l4.z, 0.2f));
        float eh = (float)exp((double)__fmul_rn(l4.w, 0.2f));
        float w  = __fmul_rn(pr.z, ew);
        float h  = __fmul_rn(pr.w, eh);
        float x1 = __fsub_rn(cx, __fmul_rn(w, 0.5f));
        float y1 = __fsub_rn(cy, __fmul_rn(h, 0.5f));
        float x2 = __fadd_rn(x1, w);
        float y2 = __fadd_rn(y1, h);
        bs[tid] = my_sc;
        bx1[tid] = x1; by1[tid] = y1; bx2[tid] = x2; by2[tid] = y2;
        bar[tid] = __fmul_rn(__fsub_rn(x2, x1), __fsub_rn(y2, y1));
    }
    __syncthreads();

    // ---- valid bits + pairwise IoU suppression masks ----
    if (tid < TOPK && my_sc > CONF_T)
        atomicOr(&vmask[tid >> 6], 1ull << (tid & 63));
    for (int idx = tid; idx < TOPK * TOPK; idx += 256) {
        int j = idx / TOPK;
        int i = idx - j * TOPK;
        if (i > j) {
            float xx1 = fmaxf(bx1[j], bx1[i]);
            float yy1 = fmaxf(by1[j], by1[i]);
            float xx2 = fminf(bx2[j], bx2[i]);
            float yy2 = fminf(by2[j], by2[i]);
            float dx = fmaxf(__fsub_rn(xx2, xx1), 0.0f);
            float dy = fmaxf(__fsub_rn(yy2, yy1), 0.0f);
            float inter = __fmul_rn(dx, dy);
            float uni = __fsub_rn(__fadd_rn(bar[j], bar[i]), inter);
            float iou = inter / uni;   // IEEE div, matches ref
            if (iou > NMS_T) atomicOr(&msk[j * 4 + (i >> 6)], 1ull << (i & 63));
        }
    }
    __syncthreads();

    // ---- greedy NMS: register-only bitmask scan on thread 0 ----
    if (tid == 0) {
        unsigned long long v0 = vmask[0], v1 = vmask[1], v2 = vmask[2], v3 = vmask[3];
        unsigned long long s0 = 0, s1 = 0, s2 = 0, s3 = 0;
        int nk = 0;
        for (int j = 0; j < TOPK; ++j) {
            unsigned long long bit = 1ull << (j & 63);
            unsigned long long vm = (j < 64) ? v0 : (j < 128) ? v1 : (j < 192) ? v2 : v3;
            unsigned long long sm = (j < 64) ? s0 : (j < 128) ? s1 : (j < 192) ? s2 : s3;
            if ((vm & bit) && !(sm & bit)) {
                order[nk++] = j;
                s0 |= msk[j * 4 + 0];
                s1 |= msk[j * 4 + 1];
                s2 |= msk[j * 4 + 2];
                s3 |= msk[j * 4 + 3];
            }
        }
        s_nk = nk;
    }
    __syncthreads();

    // ---- compacted output write ----
    const int nk = s_nk;
    for (int e = tid; e < TOPK * 5; e += 256) {
        int r = e / 5;
        int f = e - r * 5;
        float v = 0.0f;
        if (r < nk) {
            int j = order[r];
            v = (f == 0) ? bs[j] : (f == 1) ? bx1[j] : (f == 2) ? by1[j]
              : (f == 3) ? bx2[j] : by2[j];
        }
        outp[e] = v;
    }
}

extern "C" void kernel_launch(void* const* d_in, const int* in_sizes, int n_in,
                              void* d_out, int out_size, void* d_ws, size_t ws_size,
                              hipStream_t stream) {
    const float* loc   = (const float*)d_in[0];
    const float* conf  = (const float*)d_in[1];
    const float* prior = (const float*)d_in[2];
    float* out = (float*)d_out;

    const size_t need = (size_t)B_ * C_ * P_ * sizeof(float);
    if (ws_size >= need) {
        float* t = (float*)d_ws;
        transpose_conf<<<B_ * NCH, 256, 0, stream>>>(conf, t);
        detect_kernel<<<B_ * C_, 256, 0, stream>>>(loc, prior, t, 1, out);
    } else {
        detect_kernel<<<B_ * C_, 256, 0, stream>>>(loc, prior, conf, C_, out);
    }
}

// Round 2
// 190.944 us; speedup vs baseline: 1.0885x; 1.0885x over previous
//
#include <hip/hip_runtime.h>
#include <stdint.h>

#define B_ 32
#define P_ 8732
#define C_ 21
#define TOPK 200
#define CONF_T 0.01f
#define NMS_T 0.45f
#define NCH2 35        // ceil(P_/256)
#define NT 512
#define KPT 18         // ceil(P_/NT)
#define NPAIR 19900    // TOPK*(TOPK-1)/2

__device__ __forceinline__ uint32_t f2s(float f) {
    uint32_t u = __float_as_uint(f);
    return (u & 0x80000000u) ? ~u : (u | 0x80000000u);
}
__device__ __forceinline__ float s2f(uint32_t s) {
    uint32_t b = (s & 0x80000000u) ? (s & 0x7FFFFFFFu) : ~s;
    return __uint_as_float(b);
}

// conf (B,P,C) f32 -> (B,C,P) sortable-u32 keys with conf threshold applied
__global__ __launch_bounds__(256) void transpose_keys(const float* __restrict__ conf,
                                                      uint32_t* __restrict__ keys) {
    const int b = blockIdx.x / NCH2;
    const int ch = blockIdx.x % NCH2;
    const int p0 = ch * 256;
    const int n = min(256, P_ - p0);
    const int tid = threadIdx.x;
    __shared__ float tile[256 * C_];
    const float* src = conf + ((size_t)b * P_ + p0) * C_;
    const int tot = n * C_;
    for (int i = tid; i < tot; i += 256) tile[i] = src[i];
    __syncthreads();
    uint32_t* dst = keys + (size_t)b * C_ * P_ + p0;
    if (tid < n) {
        #pragma unroll
        for (int c = 0; c < C_; ++c) {
            float v = tile[tid * C_ + c];
            v = (v > CONF_T) ? v : -1.0f;
            dst[(size_t)c * P_ + tid] = f2s(v);
        }
    }
}

template<bool RAW>
__global__ __launch_bounds__(NT, 6) void detect_kernel(
    const float* __restrict__ loc, const float* __restrict__ prior,
    const uint32_t* __restrict__ keys, const float* __restrict__ conf,
    float* __restrict__ out)
{
    const int task = blockIdx.x;
    const int b = task / C_;
    const int c = task % C_;
    const int tid = threadIdx.x;
    const int lane = tid & 63;
    float* outp = out + (size_t)task * TOPK * 5;

    if (c == 0) {  // out.at[:,0].set(0.0)
        for (int e = tid; e < TOPK * 5; e += NT) outp[e] = 0.0f;
        return;
    }

    __shared__ uint32_t hist[256];
    __shared__ uint64_t cand[256];
    __shared__ float4 bbox[TOPK];
    __shared__ float bar[TOPK], bs[TOPK];
    __shared__ unsigned long long msk[TOPK * 4];
    __shared__ unsigned long long vmask[4];
    __shared__ int order[TOPK];
    __shared__ int s_cnt, s_nk;
    __shared__ uint32_t s_pref, s_want;

    // ---- load this task's keys into registers (pads = 0, below all real keys) ----
    uint32_t k_[KPT];
    if (!RAW) {
        const uint32_t* kp = keys + (size_t)task * P_;
        #pragma unroll
        for (int r = 0; r < KPT; ++r) {
            int p = tid + r * NT;
            k_[r] = (p < P_) ? kp[p] : 0u;
        }
    } else {
        const float* sp = conf + (size_t)b * P_ * C_ + c;
        #pragma unroll
        for (int r = 0; r < KPT; ++r) {
            int p = tid + r * NT;
            if (p < P_) {
                float v = sp[(size_t)p * C_];
                v = (v > CONF_T) ? v : -1.0f;
                k_[r] = f2s(v);
            } else k_[r] = 0u;
        }
    }

    // ---- radix-select the 200th-largest 32-bit key ----
    uint32_t pref = 0, want = TOPK;
    for (int level = 3; level >= 0; --level) {
        const int shift = level * 8;
        const uint32_t himask = (level == 3) ? 0u : (0xFFFFFFFFu << (shift + 8));
        if (tid < 256) hist[tid] = 0;
        __syncthreads();
        if (level == 3) {
            // ballot-aggregated histogram: one atomic per distinct bin per wave
            #pragma unroll
            for (int r = 0; r < KPT; ++r) {
                uint32_t bin = k_[r] >> 24;
                unsigned long long rem = __ballot(1);
                while (rem) {
                    int src = __ffsll(rem) - 1;
                    uint32_t bref = __shfl(bin, src);
                    unsigned long long same = __ballot(bin == bref) & rem;
                    if (lane == src) atomicAdd(&hist[bref], (uint32_t)__popcll(same));
                    rem &= ~same;
                }
            }
        } else {
            #pragma unroll
            for (int r = 0; r < KPT; ++r) {
                uint32_t u = k_[r];
                if ((u & himask) == pref) atomicAdd(&hist[(u >> shift) & 0xFFu], 1u);
            }
        }
        __syncthreads();
        if (tid == 0) {
            uint32_t cum = 0; int bin = 255;
            for (;; --bin) {
                uint32_t h = hist[bin];
                if (cum + h >= want || bin == 0) break;
                cum += h;
            }
            s_pref = pref | ((uint32_t)bin << shift);
            s_want = want - cum;
        }
        __syncthreads();
        pref = s_pref; want = s_want;
    }
    const uint32_t vthr = pref;

    // ---- compact candidates >= vthr (count in [200,256] w.o.p.) ----
    if (tid == 0) s_cnt = 0;
    __syncthreads();
    #pragma unroll
    for (int r = 0; r < KPT; ++r) {
        uint32_t u = k_[r];
        if (u >= vthr) {
            int p = tid + r * NT;
            int pos = atomicAdd(&s_cnt, 1);
            if (pos < 256) cand[pos] = ((uint64_t)u << 32) | (uint32_t)(~(uint32_t)p);
        }
    }
    __syncthreads();
    if (tid < 256 && tid >= s_cnt) cand[tid] = 0ull;
    __syncthreads();

    // ---- bitonic sort 256 keys desc (val desc, idx asc): registers + shfl_xor ----
    uint64_t v = (tid < 256) ? cand[tid] : 0ull;
    for (int kk = 2; kk <= 256; kk <<= 1) {
        for (int j = kk >> 1; j > 0; j >>= 1) {
            if (j >= 64) {
                __syncthreads();
                if (tid < 256) cand[tid] = v;
                __syncthreads();
                if (tid < 256) {
                    uint64_t pv = cand[tid ^ j];
                    bool keepmax = (((tid & j) == 0) == ((tid & kk) == 0));
                    v = keepmax ? (v > pv ? v : pv) : (v < pv ? v : pv);
                }
            } else if (tid < 256) {
                uint64_t pv = __shfl_xor(v, j);
                bool keepmax = (((tid & j) == 0) == ((tid & kk) == 0));
                v = keepmax ? (v > pv ? v : pv) : (v < pv ? v : pv);
            }
        }
    }

    // ---- decode top-200 boxes (exact ref f32 op order, no contraction) ----
    float my_sc = -1.0f;
    if (tid < TOPK) {
        uint32_t su = (uint32_t)(v >> 32);
        int p = (int)(~(uint32_t)v);
        my_sc = s2f(su);
        const float4 l4 = *(const float4*)(loc + ((size_t)b * P_ + p) * 4);
        const float4 pr = *(const float4*)(prior + (size_t)p * 4);
        float cx = __fadd_rn(pr.x, __fmul_rn(__fmul_rn(l4.x, 0.1f), pr.z));
        float cy = __fadd_rn(pr.y, __fmul_rn(__fmul_rn(l4.y, 0.1f), pr.w));
        float ew = (float)exp((double)__fmul_rn(l4.z, 0.2f));
        float eh = (float)exp((double)__fmul_rn(l4.w, 0.2f));
        float w  = __fmul_rn(pr.z, ew);
        float h  = __fmul_rn(pr.w, eh);
        float x1 = __fsub_rn(cx, __fmul_rn(w, 0.5f));
        float y1 = __fsub_rn(cy, __fmul_rn(h, 0.5f));
        float x2 = __fadd_rn(x1, w);
        float y2 = __fadd_rn(y1, h);
        bs[tid] = my_sc;
        bbox[tid] = make_float4(x1, y1, x2, y2);
        bar[tid] = __fmul_rn(__fsub_rn(x2, x1), __fsub_rn(y2, y1));
    }
    for (int i2 = tid; i2 < TOPK * 4; i2 += NT) msk[i2] = 0ull;
    {
        unsigned long long bm = __ballot(tid < TOPK && my_sc > CONF_T);
        if (lane == 0 && tid < 256) vmask[tid >> 6] = bm;
    }
    __syncthreads();

    // ---- pairwise IoU over strictly-upper triangle only ----
    for (int q = tid; q < NPAIR; q += NT) {
        int j = (int)(199.5f - sqrtf(39800.25f - 2.0f * (float)q));
        if (j < 0) j = 0;
        while ((j + 1) * (399 - (j + 1)) / 2 <= q) ++j;
        while (j * (399 - j) / 2 > q) --j;
        int i = j + 1 + (q - j * (399 - j) / 2);
        float4 bj = bbox[j];
        float4 bi = bbox[i];
        float xx1 = fmaxf(bj.x, bi.x);
        float yy1 = fmaxf(bj.y, bi.y);
        float xx2 = fminf(bj.z, bi.z);
        float yy2 = fminf(bj.w, bi.w);
        float dx = fmaxf(__fsub_rn(xx2, xx1), 0.0f);
        float dy = fmaxf(__fsub_rn(yy2, yy1), 0.0f);
        float inter = __fmul_rn(dx, dy);
        float uni = __fsub_rn(__fadd_rn(bar[j], bar[i]), inter);
        float iou = inter / uni;
        if (iou > NMS_T) atomicOr(&msk[j * 4 + (i >> 6)], 1ull << (i & 63));
    }
    __syncthreads();

    // ---- greedy NMS: register-only bitmask scan on thread 0 ----
    if (tid == 0) {
        unsigned long long v0 = vmask[0], v1 = vmask[1], v2 = vmask[2], v3 = vmask[3];
        unsigned long long s0 = 0, s1 = 0, s2 = 0, s3 = 0;
        int nk = 0;
        for (int j = 0; j < TOPK; ++j) {
            unsigned long long bit = 1ull << (j & 63);
            unsigned long long vm = (j < 64) ? v0 : (j < 128) ? v1 : (j < 192) ? v2 : v3;
            unsigned long long sm = (j < 64) ? s0 : (j < 128) ? s1 : (j < 192) ? s2 : s3;
            if ((vm & bit) && !(sm & bit)) {
                order[nk++] = j;
                s0 |= msk[j * 4 + 0];
                s1 |= msk[j * 4 + 1];
                s2 |= msk[j * 4 + 2];
                s3 |= msk[j * 4 + 3];
            }
        }
        s_nk = nk;
    }
    __syncthreads();

    // ---- compacted output ----
    const int nk = s_nk;
    for (int e = tid; e < TOPK * 5; e += NT) {
        int r = e / 5;
        int f = e - r * 5;
        float val = 0.0f;
        if (r < nk) {
            int j = order[r];
            float4 bb = bbox[j];
            val = (f == 0) ? bs[j] : (f == 1) ? bb.x : (f == 2) ? bb.y
                : (f == 3) ? bb.z : bb.w;
        }
        outp[e] = val;
    }
}

extern "C" void kernel_launch(void* const* d_in, const int* in_sizes, int n_in,
                              void* d_out, int out_size, void* d_ws, size_t ws_size,
                              hipStream_t stream) {
    const float* loc   = (const float*)d_in[0];
    const float* conf  = (const float*)d_in[1];
    const float* prior = (const float*)d_in[2];
    float* out = (float*)d_out;

    const size_t need = (size_t)B_ * C_ * P_ * sizeof(uint32_t);
    if (ws_size >= need) {
        uint32_t* keys = (uint32_t*)d_ws;
        transpose_keys<<<B_ * NCH2, 256, 0, stream>>>(conf, keys);
        detect_kernel<false><<<B_ * C_, NT, 0, stream>>>(loc, prior, keys, conf, out);
    } else {
        detect_kernel<true><<<B_ * C_, NT, 0, stream>>>(loc, prior, nullptr, conf, out);
    }
}

// Round 3
// 138.361 us; speedup vs baseline: 1.5022x; 1.3800x over previous
//
#include <hip/hip_runtime.h>
#include <stdint.h>

#define B_ 32
#define P_ 8732
#define PPAD 8736      // P_ rounded up to x4 for uint4 key loads
#define C_ 21
#define TOPK 200
#define CONF_T 0.01f
#define NMS_T 0.45f
#define NCH2 35        // ceil(P_/256)
#define NT 512
#define KV4 5          // ceil((PPAD/4)/NT)

__device__ __forceinline__ uint32_t f2s(float f) {
    uint32_t u = __float_as_uint(f);
    return (u & 0x80000000u) ? ~u : (u | 0x80000000u);
}
__device__ __forceinline__ float s2f(uint32_t s) {
    uint32_t b = (s & 0x80000000u) ? (s & 0x7FFFFFFFu) : ~s;
    return __uint_as_float(b);
}

// conf (B,P,C) f32 -> (B,C,PPAD) sortable-u32 keys, threshold applied, pads=0
__global__ __launch_bounds__(256) void transpose_keys(const float* __restrict__ conf,
                                                      uint32_t* __restrict__ keys) {
    const int b = blockIdx.x / NCH2;
    const int ch = blockIdx.x % NCH2;
    const int p0 = ch * 256;
    const int n = min(256, P_ - p0);
    const int tid = threadIdx.x;
    __shared__ float tile[256 * C_];
    const float* src = conf + ((size_t)b * P_ + p0) * C_;
    const int tot = n * C_;
    for (int i = tid; i < tot; i += 256) tile[i] = src[i];
    __syncthreads();
    uint32_t* dst = keys + (size_t)b * C_ * PPAD + p0;
    if (tid < n) {
        #pragma unroll
        for (int c = 0; c < C_; ++c) {
            float v = tile[tid * C_ + c];
            v = (v > CONF_T) ? v : -1.0f;
            dst[(size_t)c * PPAD + tid] = f2s(v);
        }
    }
    if (ch == NCH2 - 1 && tid >= n && tid < n + (PPAD - P_)) {
        #pragma unroll
        for (int c = 0; c < C_; ++c) dst[(size_t)c * PPAD + tid] = 0u;
    }
}

template<bool RAW>
__global__ __launch_bounds__(NT, 6) void detect_kernel(
    const float* __restrict__ loc, const float* __restrict__ prior,
    const uint32_t* __restrict__ keys, const float* __restrict__ conf,
    float* __restrict__ out)
{
    const int task = blockIdx.x;
    const int b = task / C_;
    const int c = task % C_;
    const int tid = threadIdx.x;
    const int lane = tid & 63;
    float* outp = out + (size_t)task * TOPK * 5;

    if (c == 0) {  // out.at[:,0].set(0.0)
        for (int e = tid; e < TOPK * 5; e += NT) outp[e] = 0.0f;
        return;
    }

    __shared__ uint32_t hist[256];
    __shared__ uint32_t wtot[4];
    __shared__ uint64_t cand[256];
    __shared__ float4 bbox[TOPK];
    __shared__ float bar[TOPK], bs[TOPK];
    __shared__ unsigned long long msk[TOPK * 4];
    __shared__ unsigned long long vmask[4];
    __shared__ int order[TOPK];
    __shared__ int s_cnt, s_nk, s_flags;
    __shared__ uint32_t s_pref, s_want;

    // ---- load this task's 8736 keys into registers as uint4 (pads = 0) ----
    uint4 kv[KV4];
    if (!RAW) {
        const uint4* kp = (const uint4*)(keys + (size_t)task * PPAD);
        #pragma unroll
        for (int r = 0; r < KV4; ++r) {
            int q = tid + r * NT;
            kv[r] = (q < PPAD / 4) ? kp[q] : make_uint4(0u, 0u, 0u, 0u);
        }
    } else {
        const float* sp = conf + (size_t)b * P_ * C_ + c;
        #pragma unroll
        for (int r = 0; r < KV4; ++r) {
            uint32_t uu[4];
            #pragma unroll
            for (int c4 = 0; c4 < 4; ++c4) {
                int p = (tid + r * NT) * 4 + c4;
                if (p < P_) {
                    float v = sp[(size_t)p * C_];
                    v = (v > CONF_T) ? v : -1.0f;
                    uu[c4] = f2s(v);
                } else uu[c4] = 0u;
            }
            kv[r] = make_uint4(uu[0], uu[1], uu[2], uu[3]);
        }
    }

    // ---- radix-select with early exit once candidate set fits in 256 ----
    uint32_t pref = 0, want = TOPK;
    for (int level = 3; level >= 0; --level) {
        const int shift = level * 8;
        const uint32_t himask = (level == 3) ? 0u : (0xFFFFFFFFu << (shift + 8));
        if (tid < 256) hist[tid] = 0;
        __syncthreads();
        if (level == 3) {
            // ballot-aggregated histogram (scores cluster into few top-byte bins)
            auto agg = [&](uint32_t u) {
                uint32_t bin = u >> 24;
                unsigned long long rem = __ballot(1);
                while (rem) {
                    int src = __ffsll(rem) - 1;
                    uint32_t bref = __shfl(bin, src);
                    unsigned long long same = __ballot(bin == bref) & rem;
                    if (lane == src) atomicAdd(&hist[bref], (uint32_t)__popcll(same));
                    rem &= ~same;
                }
            };
            #pragma unroll
            for (int r = 0; r < KV4; ++r) {
                agg(kv[r].x); agg(kv[r].y); agg(kv[r].z); agg(kv[r].w);
            }
        } else {
            auto one = [&](uint32_t u) {
                if ((u & himask) == pref) atomicAdd(&hist[(u >> shift) & 0xFFu], 1u);
            };
            #pragma unroll
            for (int r = 0; r < KV4; ++r) {
                one(kv[r].x); one(kv[r].y); one(kv[r].z); one(kv[r].w);
            }
        }
        __syncthreads();
        // parallel inclusive-suffix-sum over 256 bins (threads 0..255)
        uint32_t h = 0, I = 0;
        if (tid < 256) {
            h = hist[tid];
            I = h;
            #pragma unroll
            for (int d = 1; d < 64; d <<= 1) {
                uint32_t v = __shfl_down(I, d);
                if (lane + d < 64) I += v;
            }
            if (lane == 0) wtot[tid >> 6] = I;
        }
        __syncthreads();
        if (tid < 256) {
            uint32_t off = 0;
            for (int w2 = (tid >> 6) + 1; w2 < 4; ++w2) off += wtot[w2];
            I += off;
            uint32_t E = I - h;                 // exclusive suffix (keys above bin)
            if (I >= want && E < want) {        // unique crossing bin
                s_pref = pref | ((uint32_t)tid << shift);
                s_want = want - E;
                s_flags = ((TOPK - want) + I <= 256) ? 1 : 0;  // global qualify count
            }
        }
        __syncthreads();
        pref = s_pref; want = s_want;
        int done = s_flags;
        __syncthreads();
        if (done) break;
    }
    const uint32_t vthr = pref;   // prefix threshold; full sort below restores exactness

    // ---- compact candidates >= vthr ----
    if (tid == 0) s_cnt = 0;
    __syncthreads();
    #pragma unroll
    for (int r = 0; r < KV4; ++r) {
        const int pb = (tid + r * NT) * 4;
        uint32_t uu[4] = {kv[r].x, kv[r].y, kv[r].z, kv[r].w};
        #pragma unroll
        for (int c4 = 0; c4 < 4; ++c4) {
            uint32_t u = uu[c4];
            if (u >= vthr) {
                int pos = atomicAdd(&s_cnt, 1);
                if (pos < 256) cand[pos] = ((uint64_t)u << 32) | (uint32_t)(~(uint32_t)(pb + c4));
            }
        }
    }
    __syncthreads();
    if (tid < 256 && tid >= s_cnt) cand[tid] = 0ull;
    __syncthreads();

    // ---- bitonic sort 256 keys desc (val desc, idx asc) == jax.lax.top_k ----
    uint64_t v = (tid < 256) ? cand[tid] : 0ull;
    for (int kk = 2; kk <= 256; kk <<= 1) {
        for (int j = kk >> 1; j > 0; j >>= 1) {
            if (j >= 64) {
                __syncthreads();
                if (tid < 256) cand[tid] = v;
                __syncthreads();
                if (tid < 256) {
                    uint64_t pv = cand[tid ^ j];
                    bool keepmax = (((tid & j) == 0) == ((tid & kk) == 0));
                    v = keepmax ? (v > pv ? v : pv) : (v < pv ? v : pv);
                }
            } else if (tid < 256) {
                uint64_t pv = __shfl_xor(v, j);
                bool keepmax = (((tid & j) == 0) == ((tid & kk) == 0));
                v = keepmax ? (v > pv ? v : pv) : (v < pv ? v : pv);
            }
        }
    }

    // ---- decode top-200 boxes (exact ref f32 op order, no contraction) ----
    float my_sc = -1.0f;
    if (tid < TOPK) {
        uint32_t su = (uint32_t)(v >> 32);
        int p = (int)(~(uint32_t)v);
        my_sc = s2f(su);
        const float4 l4 = *(const float4*)(loc + ((size_t)b * P_ + p) * 4);
        const float4 pr = *(const float4*)(prior + (size_t)p * 4);
        float cx = __fadd_rn(pr.x, __fmul_rn(__fmul_rn(l4.x, 0.1f), pr.z));
        float cy = __fadd_rn(pr.y, __fmul_rn(__fmul_rn(l4.y, 0.1f), pr.w));
        float ew = (float)exp((double)__fmul_rn(l4.z, 0.2f));
        float eh = (float)exp((double)__fmul_rn(l4.w, 0.2f));
        float w  = __fmul_rn(pr.z, ew);
        float h  = __fmul_rn(pr.w, eh);
        float x1 = __fsub_rn(cx, __fmul_rn(w, 0.5f));
        float y1 = __fsub_rn(cy, __fmul_rn(h, 0.5f));
        float x2 = __fadd_rn(x1, w);
        float y2 = __fadd_rn(y1, h);
        bs[tid] = my_sc;
        bbox[tid] = make_float4(x1, y1, x2, y2);
        bar[tid] = __fmul_rn(__fsub_rn(x2, x1), __fsub_rn(y2, y1));
    }
    for (int i2 = tid; i2 < TOPK * 4; i2 += NT) msk[i2] = 0ull;
    {
        unsigned long long bm = __ballot(tid < TOPK && my_sc > CONF_T);
        if (lane == 0 && tid < 256) vmask[tid >> 6] = bm;
    }
    __syncthreads();

    // ---- pairwise IoU: balanced row-pairing, div screened to a tie band ----
    if (tid < 500) {
        const int rp = tid / 5;        // row-pair id in [0,100)
        const int s  = tid - rp * 5;   // sub-lane in [0,5)
        #pragma unroll
        for (int pass = 0; pass < 2; ++pass) {
            const int j  = pass ? (199 - rp) : rp;
            const int i0 = pass ? (200 - rp + s) : (rp + 1 + s);
            const float4 bj = bbox[j];
            const float  aj = bar[j];
            for (int i = i0; i < TOPK; i += 5) {
                const float4 bi = bbox[i];
                float xx1 = fmaxf(bj.x, bi.x);
                float yy1 = fmaxf(bj.y, bi.y);
                float xx2 = fminf(bj.z, bi.z);
                float yy2 = fminf(bj.w, bi.w);
                float dx = fmaxf(__fsub_rn(xx2, xx1), 0.0f);
                float dy = fmaxf(__fsub_rn(yy2, yy1), 0.0f);
                float inter = __fmul_rn(dx, dy);
                if (inter > 0.0f) {
                    float uni = __fsub_rn(__fadd_rn(aj, bar[i]), inter);
                    float t45 = __fmul_rn(NMS_T, uni);
                    float mar = __fmul_rn(t45, 1e-6f);
                    bool sup;
                    if (inter > __fadd_rn(t45, mar)) sup = true;
                    else if (inter < __fsub_rn(t45, mar)) sup = false;
                    else sup = (inter / uni > NMS_T);   // exact IEEE path, tie band only
                    if (sup) atomicOr(&msk[j * 4 + (i >> 6)], 1ull << (i & 63));
                }
            }
        }
    }
    __syncthreads();

    // ---- greedy NMS: wave-0-parallel bitmask scan, rows in lane registers ----
    if (tid < 64) {
        const int L = tid;
        unsigned long long s0 = 0, s1 = 0, s2 = 0, s3 = 0;
        const unsigned long long vm0 = vmask[0], vm1 = vmask[1],
                                 vm2 = vmask[2], vm3 = vmask[3];
        int nk = 0;
        #pragma unroll
        for (int w = 0; w < 4; ++w) {
            const int j = (w << 6) | L;
            unsigned long long r0 = 0, r1 = 0, r2 = 0, r3 = 0;
            if (j < TOPK) {
                const unsigned long long* mr = &msk[j * 4];
                r0 = mr[0]; r1 = mr[1]; r2 = mr[2]; r3 = mr[3];
            }
            const unsigned long long vw = (w == 0) ? vm0 : (w == 1) ? vm1
                                        : (w == 2) ? vm2 : vm3;
            const unsigned long long sw = (w == 0) ? s0 : (w == 1) ? s1
                                        : (w == 2) ? s2 : s3;
            unsigned long long alive = vw & ~sw;
            while (alive) {
                int jl = __ffsll(alive) - 1;
                if (L == 0) order[nk] = (w << 6) | jl;
                ++nk;
                s0 |= __shfl(r0, jl); s1 |= __shfl(r1, jl);
                s2 |= __shfl(r2, jl); s3 |= __shfl(r3, jl);
                const unsigned long long swn = (w == 0) ? s0 : (w == 1) ? s1
                                             : (w == 2) ? s2 : s3;
                alive &= ~swn;
                alive &= ~(1ull << jl);
            }
        }
        if (L == 0) s_nk = nk;
    }
    __syncthreads();

    // ---- compacted output ----
    const int nk = s_nk;
    for (int e = tid; e < TOPK * 5; e += NT) {
        int r = e / 5;
        int f = e - r * 5;
        float val = 0.0f;
        if (r < nk) {
            int j = order[r];
            float4 bb = bbox[j];
            val = (f == 0) ? bs[j] : (f == 1) ? bb.x : (f == 2) ? bb.y
                : (f == 3) ? bb.z : bb.w;
        }
        outp[e] = val;
    }
}

extern "C" void kernel_launch(void* const* d_in, const int* in_sizes, int n_in,
                              void* d_out, int out_size, void* d_ws, size_t ws_size,
                              hipStream_t stream) {
    const float* loc   = (const float*)d_in[0];
    const float* conf  = (const float*)d_in[1];
    const float* prior = (const float*)d_in[2];
    float* out = (float*)d_out;

    const size_t need = (size_t)B_ * C_ * PPAD * sizeof(uint32_t);
    if (ws_size >= need) {
        uint32_t* keys = (uint32_t*)d_ws;
        transpose_keys<<<B_ * NCH2, 256, 0, stream>>>(conf, keys);
        detect_kernel<false><<<B_ * C_, NT, 0, stream>>>(loc, prior, keys, conf, out);
    } else {
        detect_kernel<true><<<B_ * C_, NT, 0, stream>>>(loc, prior, nullptr, conf, out);
    }
}